// Round 1
// baseline (689.780 us; speedup 1.0000x reference)
//
#include <hip/hip_runtime.h>
#include <stdint.h>

typedef __bf16 bf16;
typedef __attribute__((ext_vector_type(8))) __bf16 bf16x8;
typedef __attribute__((ext_vector_type(4))) float f32x4;

#define N_TOK 8192
#define C_DIM 1024
#define I_DIM 1408
#define NE 8      // routed experts
#define NEA 9     // + shared expert as slot 8

// ---- workspace byte offsets ----
#define CNT_OFF   0
#define OFFS_OFF  64
#define BTOK_OFF  128
#define BP_OFF    (BTOK_OFF + NE * N_TOK * 4)   // 262272
#define ROUTER_END (BP_OFF + NE * N_TOK * 4)    // 524416
#define XB_OFF    (1u << 20)                    // x as bf16: 16 MB
#define WB1_OFF   (18u << 20)                   // [9][I][C] bf16: 24.75 MB
#define WB2_OFF   (43u << 20)
#define WB3_OFF   (68u << 20)                   // [9][C][I] bf16
#define H_OFF     (93u << 20)                   // 25600 x I bf16: 68.75 MB

__device__ __forceinline__ void gload16(const void* g, void* l) {
  __builtin_amdgcn_global_load_lds(
      (const __attribute__((address_space(1))) void*)g,
      (__attribute__((address_space(3))) void*)l, 16, 0, 0);
}

// ---------------- conversion fp32 -> bf16, 8 elems/thread ----------------
__global__ __launch_bounds__(256) void convert_kernel(
    const float* __restrict__ src, bf16* __restrict__ dst, int n8) {
  int i = blockIdx.x * 256 + threadIdx.x;
  if (i >= n8) return;
  const float* s = src + (size_t)i * 8;
  float4 a = *(const float4*)(s);
  float4 b = *(const float4*)(s + 4);
  bf16x8 v;
  v[0] = (bf16)a.x; v[1] = (bf16)a.y; v[2] = (bf16)a.z; v[3] = (bf16)a.w;
  v[4] = (bf16)b.x; v[5] = (bf16)b.y; v[6] = (bf16)b.z; v[7] = (bf16)b.w;
  *(bf16x8*)(dst + (size_t)i * 8) = v;
}

// ---------------- router: wave per token ----------------
__global__ __launch_bounds__(256) void router_kernel(
    const float* __restrict__ x, const float* __restrict__ Wg,
    int* __restrict__ cnt, int* __restrict__ btok, float* __restrict__ bp) {
  __shared__ __align__(16) float wg[NE * C_DIM];
  int t = threadIdx.x;
#pragma unroll
  for (int j = 0; j < 8; ++j) {
    int idx = (t + 256 * j) * 4;
    *(float4*)&wg[idx] = *(const float4*)&Wg[idx];
  }
  __syncthreads();
  int wid = t >> 6, lane = t & 63;
  int tok = blockIdx.x * 4 + wid;
  const float* xr = x + (size_t)tok * C_DIM;
  float acc[NE];
#pragma unroll
  for (int e = 0; e < NE; ++e) acc[e] = 0.f;
#pragma unroll
  for (int j = 0; j < 4; ++j) {
    int c4 = (lane + 64 * j) * 4;
    float4 xv = *(const float4*)&xr[c4];
#pragma unroll
    for (int e = 0; e < NE; ++e) {
      float4 wv = *(const float4*)&wg[e * C_DIM + c4];
      acc[e] += xv.x * wv.x + xv.y * wv.y + xv.z * wv.z + xv.w * wv.w;
    }
  }
  for (int o = 32; o >= 1; o >>= 1)
#pragma unroll
    for (int e = 0; e < NE; ++e) acc[e] += __shfl_xor(acc[e], o, 64);
  if (lane == 0) {
    float m = acc[0];
#pragma unroll
    for (int e = 1; e < NE; ++e) m = fmaxf(m, acc[e]);
    float p[NE], s = 0.f;
#pragma unroll
    for (int e = 0; e < NE; ++e) { p[e] = __expf(acc[e] - m); s += p[e]; }
    float inv = 1.f / s;
#pragma unroll
    for (int e = 0; e < NE; ++e) p[e] *= inv;
    int e0 = 0; float p0 = p[0];
#pragma unroll
    for (int e = 1; e < NE; ++e) if (p[e] > p0) { p0 = p[e]; e0 = e; }
    int e1 = -1; float p1 = -1.f;
#pragma unroll
    for (int e = 0; e < NE; ++e) {
      if (e == e0) continue;
      if (p[e] > p1) { p1 = p[e]; e1 = e; }
    }
    int pos0 = atomicAdd(&cnt[e0], 1);
    btok[e0 * N_TOK + pos0] = tok; bp[e0 * N_TOK + pos0] = p0;
    int pos1 = atomicAdd(&cnt[e1], 1);
    btok[e1 * N_TOK + pos1] = tok; bp[e1 * N_TOK + pos1] = p1;
  }
}

__global__ void offsets_kernel(const int* __restrict__ cnt, int* __restrict__ offs) {
  if (threadIdx.x == 0) {
    int a = 0;
    for (int e = 0; e < NE; ++e) { offs[e] = a; a += (cnt[e] + 127) & ~127; }
    offs[NE] = a;
  }
}

// swizzled ds_read byte offset for (row, kgroup) in a [128][32] bf16 tile
__device__ __forceinline__ int swz_off(int row, int kg) {
  return row * 64 + ((kg ^ ((row >> 1) & 3)) * 16);
}

// ---------------- stage1: H = silu(X W1^T) * (X W2^T), per expert ----------------
__global__ __launch_bounds__(512) void stage1_kernel(
    const bf16* __restrict__ xb, const bf16* __restrict__ wb1,
    const bf16* __restrict__ wb2, const int* __restrict__ cnt,
    const int* __restrict__ offs, const int* __restrict__ btok,
    bf16* __restrict__ H) {
  int e = blockIdx.z;
  int row0 = blockIdx.x * 128;
  int padded = (e == NE) ? N_TOK : ((cnt[e] + 127) & ~127);
  if (row0 >= padded) return;
  int i0 = blockIdx.y * 128;
  int slotbase = (e == NE) ? 0 : (N_TOK + offs[e]);

  __shared__ __align__(16) char smem[49152];  // 2 x (A 8K | B1 8K | B2 8K)
  int t = threadIdx.x;
  int lane = t & 63, wid = t >> 6;
  int wr = wid >> 2, wc = wid & 3;

  int srow = t >> 2;
  int gsrc = (t & 3) ^ ((srow >> 1) & 3);  // inverse-swizzled source segment
  int aidx = row0 + srow;
  int atok = (e == NE) ? aidx : btok[e * N_TOK + aidx];
  const bf16* aptr = xb + (size_t)atok * C_DIM + gsrc * 8;
  const bf16* b1p = wb1 + ((size_t)e * I_DIM + i0 + srow) * C_DIM + gsrc * 8;
  const bf16* b2p = wb2 + ((size_t)e * I_DIM + i0 + srow) * C_DIM + gsrc * 8;

  f32x4 accG[4][2], accU[4][2];
  f32x4 zero = {0.f, 0.f, 0.f, 0.f};
#pragma unroll
  for (int mf = 0; mf < 4; ++mf)
#pragma unroll
    for (int nf = 0; nf < 2; ++nf) { accG[mf][nf] = zero; accU[mf][nf] = zero; }

  int l15 = lane & 15, kg = lane >> 4;
  int aoff[4], boff[2];
#pragma unroll
  for (int mf = 0; mf < 4; ++mf) aoff[mf] = swz_off(wr * 64 + mf * 16 + l15, kg);
#pragma unroll
  for (int nf = 0; nf < 2; ++nf) boff[nf] = swz_off(wc * 32 + nf * 16 + l15, kg);

  auto stage = [&](int b, int k0) {
    char* base = smem + b * 24576;
    gload16(aptr + k0, base + t * 16);
    gload16(b1p + k0, base + 8192 + t * 16);
    gload16(b2p + k0, base + 16384 + t * 16);
  };

  stage(0, 0);
  __syncthreads();
  int cur = 0;
  for (int kt = 0; kt < C_DIM / 32; ++kt) {
    if (kt + 1 < C_DIM / 32) stage(cur ^ 1, (kt + 1) * 32);
    char* base = smem + cur * 24576;
    bf16x8 a[4], v1[2], v2[2];
#pragma unroll
    for (int mf = 0; mf < 4; ++mf) a[mf] = *(const bf16x8*)(base + aoff[mf]);
#pragma unroll
    for (int nf = 0; nf < 2; ++nf) {
      v1[nf] = *(const bf16x8*)(base + 8192 + boff[nf]);
      v2[nf] = *(const bf16x8*)(base + 16384 + boff[nf]);
    }
#pragma unroll
    for (int mf = 0; mf < 4; ++mf)
#pragma unroll
      for (int nf = 0; nf < 2; ++nf) {
        accG[mf][nf] = __builtin_amdgcn_mfma_f32_16x16x32_bf16(a[mf], v1[nf], accG[mf][nf], 0, 0, 0);
        accU[mf][nf] = __builtin_amdgcn_mfma_f32_16x16x32_bf16(a[mf], v2[nf], accU[mf][nf], 0, 0, 0);
      }
    __syncthreads();
    cur ^= 1;
  }

#pragma unroll
  for (int mf = 0; mf < 4; ++mf)
#pragma unroll
    for (int nf = 0; nf < 2; ++nf)
#pragma unroll
      for (int r = 0; r < 4; ++r) {
        float g = accG[mf][nf][r];
        float u = accU[mf][nf][r];
        float h = (g / (1.f + __expf(-g))) * u;
        int row = row0 + wr * 64 + mf * 16 + (lane >> 4) * 4 + r;
        int col = i0 + wc * 32 + nf * 16 + l15;
        H[(size_t)(slotbase + row) * I_DIM + col] = (bf16)h;
      }
}

// ---------------- stage2: y (+)= p * (H W3^T) ----------------
template <int ATOMIC>
__global__ __launch_bounds__(512) void stage2_kernel(
    const bf16* __restrict__ H, const bf16* __restrict__ wb3,
    const int* __restrict__ cnt, const int* __restrict__ offs,
    const int* __restrict__ btok, const float* __restrict__ bp,
    float* __restrict__ y) {
  int e = ATOMIC ? blockIdx.z : NE;
  int row0 = blockIdx.x * 128;
  int padded = ATOMIC ? ((cnt[e] + 127) & ~127) : N_TOK;
  if (row0 >= padded) return;
  int c0 = blockIdx.y * 128;
  int slotbase = ATOMIC ? (N_TOK + offs[e]) : 0;

  __shared__ __align__(16) char smem[32768];  // 2 x (A 8K | B 8K)
  int t = threadIdx.x;
  int lane = t & 63, wid = t >> 6;
  int wr = wid >> 2, wc = wid & 3;

  int srow = t >> 2;
  int gsrc = (t & 3) ^ ((srow >> 1) & 3);
  const bf16* aptr = H + (size_t)(slotbase + row0 + srow) * I_DIM + gsrc * 8;
  const bf16* b3p = wb3 + ((size_t)e * C_DIM + c0 + srow) * I_DIM + gsrc * 8;

  f32x4 acc[4][2];
  f32x4 zero = {0.f, 0.f, 0.f, 0.f};
#pragma unroll
  for (int mf = 0; mf < 4; ++mf)
#pragma unroll
    for (int nf = 0; nf < 2; ++nf) acc[mf][nf] = zero;

  int l15 = lane & 15, kg = lane >> 4;
  int aoff[4], boff[2];
#pragma unroll
  for (int mf = 0; mf < 4; ++mf) aoff[mf] = swz_off(wr * 64 + mf * 16 + l15, kg);
#pragma unroll
  for (int nf = 0; nf < 2; ++nf) boff[nf] = swz_off(wc * 32 + nf * 16 + l15, kg);

  auto stage = [&](int b, int k0) {
    char* base = smem + b * 16384;
    gload16(aptr + k0, base + t * 16);
    gload16(b3p + k0, base + 8192 + t * 16);
  };

  stage(0, 0);
  __syncthreads();
  int cur = 0;
  for (int kt = 0; kt < I_DIM / 32; ++kt) {
    if (kt + 1 < I_DIM / 32) stage(cur ^ 1, (kt + 1) * 32);
    char* base = smem + cur * 16384;
    bf16x8 a[4], b[2];
#pragma unroll
    for (int mf = 0; mf < 4; ++mf) a[mf] = *(const bf16x8*)(base + aoff[mf]);
#pragma unroll
    for (int nf = 0; nf < 2; ++nf) b[nf] = *(const bf16x8*)(base + 8192 + boff[nf]);
#pragma unroll
    for (int mf = 0; mf < 4; ++mf)
#pragma unroll
      for (int nf = 0; nf < 2; ++nf)
        acc[mf][nf] = __builtin_amdgcn_mfma_f32_16x16x32_bf16(a[mf], b[nf], acc[mf][nf], 0, 0, 0);
    __syncthreads();
    cur ^= 1;
  }

#pragma unroll
  for (int mf = 0; mf < 4; ++mf)
#pragma unroll
    for (int r = 0; r < 4; ++r) {
      int idx = row0 + wr * 64 + mf * 16 + (lane >> 4) * 4 + r;
#pragma unroll
      for (int nf = 0; nf < 2; ++nf) {
        float o = acc[mf][nf][r];
        int col = c0 + wc * 32 + nf * 16 + l15;
        if (ATOMIC) {
          float p = bp[e * N_TOK + idx];
          int tok = btok[e * N_TOK + idx];
          atomicAdd(&y[(size_t)tok * C_DIM + col], p * o);
        } else {
          y[(size_t)idx * C_DIM + col] = o;
        }
      }
    }
}

extern "C" void kernel_launch(void* const* d_in, const int* in_sizes, int n_in,
                              void* d_out, int out_size, void* d_ws, size_t ws_size,
                              hipStream_t stream) {
  const float* x = (const float*)d_in[0];
  const float* Wg = (const float*)d_in[1];
  const float* W1 = (const float*)d_in[2];
  const float* W2 = (const float*)d_in[3];
  const float* W3 = (const float*)d_in[4];
  const float* Ws1 = (const float*)d_in[5];
  const float* Ws2 = (const float*)d_in[6];
  const float* Ws3 = (const float*)d_in[7];
  float* y = (float*)d_out;
  char* ws = (char*)d_ws;

  int* cnt = (int*)(ws + CNT_OFF);
  int* offs = (int*)(ws + OFFS_OFF);
  int* btok = (int*)(ws + BTOK_OFF);
  float* bp = (float*)(ws + BP_OFF);
  bf16* xb = (bf16*)(ws + XB_OFF);
  bf16* wb1 = (bf16*)(ws + WB1_OFF);
  bf16* wb2 = (bf16*)(ws + WB2_OFF);
  bf16* wb3 = (bf16*)(ws + WB3_OFF);
  bf16* H = (bf16*)(ws + H_OFF);

  hipMemsetAsync(ws, 0, ROUTER_END, stream);

  auto conv = [&](const float* s, bf16* d, size_t n) {
    int n8 = (int)(n / 8);
    convert_kernel<<<(n8 + 255) / 256, 256, 0, stream>>>(s, d, n8);
  };
  conv(x, xb, (size_t)N_TOK * C_DIM);
  conv(W1, wb1, (size_t)NE * I_DIM * C_DIM);
  conv(Ws1, wb1 + (size_t)NE * I_DIM * C_DIM, (size_t)I_DIM * C_DIM);
  conv(W2, wb2, (size_t)NE * I_DIM * C_DIM);
  conv(Ws2, wb2 + (size_t)NE * I_DIM * C_DIM, (size_t)I_DIM * C_DIM);
  conv(W3, wb3, (size_t)NE * C_DIM * I_DIM);
  conv(Ws3, wb3 + (size_t)NE * C_DIM * I_DIM, (size_t)C_DIM * I_DIM);

  router_kernel<<<N_TOK / 4, 256, 0, stream>>>(x, Wg, cnt, btok, bp);
  offsets_kernel<<<1, 64, 0, stream>>>(cnt, offs);

  stage1_kernel<<<dim3(64, 11, NEA), 512, 0, stream>>>(xb, wb1, wb2, cnt, offs, btok, H);
  stage2_kernel<0><<<dim3(64, 8, 1), 512, 0, stream>>>(H, wb3, cnt, offs, btok, bp, y);
  stage2_kernel<1><<<dim3(64, 8, NE), 512, 0, stream>>>(H, wb3, cnt, offs, btok, bp, y);
}